// Round 11
// baseline (681.830 us; speedup 1.0000x reference)
//
#include <hip/hip_runtime.h>

#define C_ 256
#define T_ 16
#define H_ 64
#define W_ 64
#define PT 5
#define PH 8
#define PW 8
#define OT 4
#define OH 7
#define OW 7
#define SSCALE (1.0f/16.0f)
#define TSCALE 1.0f
#define CG 64               /* channels per roi block */
#define LROW 66             /* plane col stride: 8B-aligned f2v pool reads */
#define PLN (CG * LROW)     /* 4224 floats per plane buffer */
#define NOUT (CG * OT * OH * OW)   /* 12544 outputs per block */

typedef float f4v __attribute__((ext_vector_type(4)));
typedef float f2v __attribute__((ext_vector_type(2)));
typedef _Float16 h2v __attribute__((ext_vector_type(2)));
typedef _Float16 h8v __attribute__((ext_vector_type(8)));

__device__ __forceinline__ f4v lo4(h8v h) {
    f4v r = {(float)h[0], (float)h[1], (float)h[2], (float)h[3]};
    return r;
}
__device__ __forceinline__ f4v hi4(h8v h) {
    f4v r = {(float)h[4], (float)h[5], (float)h[6], (float)h[7]};
    return r;
}

// ---------------- transpose+cvt (B,C,T,H,W) f32 -> (B,T,H,W,C) fp16 ----------------
// Read-roofline-bound. The LAST x-block (blockIdx.x == gridDim.x-1, y==0) runs
// the Morton roi sort CONCURRENTLY with the transpose (no serial sort dispatch).
__global__ __launch_bounds__(256) void transpose_kernel(const float* __restrict__ f,
                                                        _Float16* __restrict__ ft,
                                                        const float* __restrict__ rois,
                                                        int nroi, int* __restrict__ perm) {
    __shared__ unsigned tile[64 * 128];   // 32 KB (sort reuses first 8 KB)
    const int THW = T_ * H_ * W_;

    if (blockIdx.x == gridDim.x - 1) {    // sort block (grid.x = THW/64 + 1)
        if (blockIdx.y != 0) return;
        unsigned* key = tile;
        int t = threadIdx.x;
        if (nroi > 2048) {
            for (int i = t; i < nroi; i += 256) perm[i] = i;
            return;
        }
        for (int i = t; i < 2048; i += 256) {
            unsigned k = 0x1FFFFFu;
            if (i < nroi) {
                const float* rp = rois + i * 7;
                int bb = (int)rp[0];
                float xc = (rp[1] + rp[3]) * 0.5f * SSCALE;
                float yc = (rp[2] + rp[4]) * 0.5f * SSCALE;
                float tc = (rp[5] + rp[6]) * 0.5f * TSCALE;
                int xq = min(63, max(0, (int)xc));
                int yq = min(63, max(0, (int)yc));
                int tq = min(15, max(0, (int)tc));
                unsigned m = 0;
#pragma unroll
                for (int bit = 0; bit < 6; ++bit)
                    m |= (((yq >> bit) & 1u) << (2 * bit + 1)) |
                         (((xq >> bit) & 1u) << (2 * bit));
                k = ((((unsigned)bb << 12) | m) << 4) | (unsigned)tq;
            }
            key[i] = (k << 11) | (unsigned)i;
        }
        __syncthreads();
        for (int kk = 2; kk <= 2048; kk <<= 1) {
            for (int j = kk >> 1; j > 0; j >>= 1) {
                for (int i = t; i < 2048; i += 256) {
                    int ixj = i ^ j;
                    if (ixj > i) {
                        unsigned a = key[i], c = key[ixj];
                        bool up = (i & kk) == 0;
                        if ((a > c) == up) { key[i] = c; key[ixj] = a; }
                    }
                }
                __syncthreads();
            }
        }
        for (int i = t; i < 2048; i += 256)
            if (i < nroi) perm[i] = (int)(key[i] & 0x7FFu);
        return;
    }

    // ---- transpose path: channel-pair packed u32 tile, XOR swizzle ----
    int thw0 = blockIdx.x * 64;
    int b = blockIdx.y;
    int q = threadIdx.x & 15;      // thw quad
    int cp0 = threadIdx.x >> 4;    // 0..15

#pragma unroll
    for (int k = 0; k < 8; ++k) {
        int cp = k * 16 + cp0;     // channel pair 0..127
        int c = cp * 2;
        const f4v* s0 = reinterpret_cast<const f4v*>(
            &f[((size_t)b * C_ + c) * THW + thw0 + q * 4]);
        const f4v* s1 = reinterpret_cast<const f4v*>(
            &f[((size_t)b * C_ + c + 1) * THW + thw0 + q * 4]);
        f4v va = __builtin_nontemporal_load(s0);
        f4v vb = __builtin_nontemporal_load(s1);
#pragma unroll
        for (int j = 0; j < 4; ++j) {
            int row = q * 4 + j;
            h2v hp = {(_Float16)va[j], (_Float16)vb[j]};
            tile[row * 128 + (cp ^ (row & 30))] = __builtin_bit_cast(unsigned, hp);
        }
    }
    __syncthreads();

    int wv = threadIdx.x >> 6;     // wave 0..3
    int ln = threadIdx.x & 63;
    size_t orow = ((size_t)b * THW + thw0) * C_;
#pragma unroll
    for (int i = 0; i < 16; ++i) {
        int row = wv * 16 + i;
        int s = row & 30;          // even -> pair-preserving XOR -> b64 read
        uint2 w = *reinterpret_cast<const uint2*>(&tile[row * 128 + ((ln * 2) ^ s)]);
        *reinterpret_cast<uint2*>(&ft[orow + (size_t)row * C_ + ln * 4]) = w;
    }
}

// ---------------- main: one 512-thread block per (sorted roi, 64-channel group) ----
// Rolling 2-entry row-plane cache (loads 40 -> ~16-24/thread). LDS cut to the
// 33.8KB plane dbuf (flush split into 2 t-pair passes staged in the dead dbuf
// region) -> 4 blocks/CU; launch_bounds(512,8) forces VGPR<=64 for 32 waves.
__global__ __launch_bounds__(512, 8) void roi_kernel(const _Float16* __restrict__ ft,
                                                     const float* __restrict__ rois,
                                                     const int* __restrict__ perm,
                                                     float* __restrict__ out) {
    __shared__ float scratch[2 * PLN];  // 33792 B: plane dbuf; later flush staging
    __shared__ float sroi[7];
    __shared__ int2 s_trow[PT]; __shared__ float2 s_twt[PT];
    __shared__ int2 s_yrow[PH]; __shared__ float2 s_ywt[PH];
    __shared__ int2 s_xoff[PW]; __shared__ float2 s_xwt[PW];

    int bid = blockIdx.x;
    int r = perm[bid >> 2];
    int cg = bid & 3;
    int c0 = cg * CG;

    if (threadIdx.x < 7) sroi[threadIdx.x] = rois[r * 7 + threadIdx.x];
    __syncthreads();

    // axis tables: byte offsets (lo/hi) + validity-folded weights
    if (threadIdx.x < 21) {
        int i = threadIdx.x;
        float start, end, size;
        int j, n, scale;
        if (i < 5) {
            j = i; n = PT;
            start = sroi[5] * TSCALE; end = sroi[6] * TSCALE;
            size = (float)T_; scale = H_ * W_ * C_ * 2;
        } else if (i < 13) {
            j = i - 5; n = PH;
            start = sroi[2] * SSCALE; end = sroi[4] * SSCALE;
            size = (float)H_; scale = W_ * C_ * 2;
        } else {
            j = i - 13; n = PW;
            start = sroi[1] * SSCALE; end = sroi[3] * SSCALE;
            size = (float)W_; scale = C_ * 2;
        }
        float length = fmaxf(end - start + 1.0f, 1.0f);
        float step = length / (float)(n - 1);
        float coord = start + step * (float)j;
        float valid = (coord >= 0.0f && coord < size) ? 1.0f : 0.0f;
        float lo = fminf(fmaxf(floorf(coord), 0.0f), size - 1.0f);
        int lo_i = (int)lo;
        int hi_i = min(lo_i + 1, (int)size - 1);
        float fr = coord - lo;
        int2 offs; offs.x = lo_i * scale; offs.y = hi_i * scale;
        float2 wts; wts.x = (1.0f - fr) * valid; wts.y = fr * valid;
        if (i < 5)       { s_trow[j] = offs; s_twt[j] = wts; }
        else if (i < 13) { s_yrow[j] = offs; s_ywt[j] = wts; }
        else             { s_xoff[j] = offs; s_xwt[j] = wts; }
    }
    __syncthreads();

    int b = (int)sroi[0];
    int c8 = threadIdx.x & 7;     // half8 lane: 8 lanes x 8 ch = 64 channels
    int slot = threadIdx.x >> 3;  // 0..63 sample slot
    const char* fb = (const char*)ft
        + ((size_t)b * (T_ * H_ * W_ * C_) + (size_t)(c0 + c8 * 8)) * 2;

    float* bufs[2] = {scratch, scratch + PLN};
    int cc = threadIdx.x & 63;
    int hh = threadIdx.x >> 6;    // 0..7; hh==7 idle for pooling

    float racc[OT][OW];
#pragma unroll
    for (int t = 0; t < OT; ++t)
#pragma unroll
        for (int w = 0; w < OW; ++w) racc[t][w] = 0.0f;

    int y = slot >> 3, x = slot & 7;
    int2 yr = s_yrow[y]; float2 yw = s_ywt[y];
    int2 xo = s_xoff[x]; float2 xw = s_xwt[x];
    int o00 = yr.x + xo.x, o01 = yr.x + xo.y;
    int o10 = yr.y + xo.x, o11 = yr.y + xo.y;

    // rolling row-plane cache: slot A (row ia), slot B (row ib)
    int ia = -1, ib = -1;
    f4v aL, aH, bL, bH;
    aL = aH = bL = bH = (f4v){0.f, 0.f, 0.f, 0.f};

#pragma unroll
    for (int t = 0; t < PT; ++t) {
        int2 trv = s_trow[t];
        int trx = __builtin_amdgcn_readfirstlane(trv.x);
        int trY = __builtin_amdgcn_readfirstlane(trv.y);
        float2 tw = s_twt[t];

        if (ia != trx) {
            if (ib == trx) { aL = bL; aH = bH; ia = trx; }
            else {
                h8v q00 = *(const h8v*)(fb + trx + o00);
                h8v q01 = *(const h8v*)(fb + trx + o01);
                h8v q10 = *(const h8v*)(fb + trx + o10);
                h8v q11 = *(const h8v*)(fb + trx + o11);
                aL = yw.x * (xw.x * lo4(q00) + xw.y * lo4(q01))
                   + yw.y * (xw.x * lo4(q10) + xw.y * lo4(q11));
                aH = yw.x * (xw.x * hi4(q00) + xw.y * hi4(q01))
                   + yw.y * (xw.x * hi4(q10) + xw.y * hi4(q11));
                ia = trx;
            }
        }
        if (ib != trY) {
            if (ia == trY) { bL = aL; bH = aH; ib = trY; }
            else {
                h8v p00 = *(const h8v*)(fb + trY + o00);
                h8v p01 = *(const h8v*)(fb + trY + o01);
                h8v p10 = *(const h8v*)(fb + trY + o10);
                h8v p11 = *(const h8v*)(fb + trY + o11);
                bL = yw.x * (xw.x * lo4(p00) + xw.y * lo4(p01))
                   + yw.y * (xw.x * lo4(p10) + xw.y * lo4(p11));
                bH = yw.x * (xw.x * hi4(p00) + xw.y * hi4(p01))
                   + yw.y * (xw.x * hi4(p10) + xw.y * hi4(p11));
                ib = trY;
            }
        }

        f4v vL = tw.x * aL + tw.y * bL;
        f4v vH = tw.x * aH + tw.y * bH;

        float* bp = bufs[t & 1];
        {
            float* col = &bp[(c8 * 8) * LROW + slot];
            col[0 * LROW] = vL[0];
            col[1 * LROW] = vL[1];
            col[2 * LROW] = vL[2];
            col[3 * LROW] = vL[3];
            col[4 * LROW] = vH[0];
            col[5 * LROW] = vH[1];
            col[6 * LROW] = vH[2];
            col[7 * LROW] = vH[3];
        }
        __syncthreads();   // single barrier/plane: next write hits other buffer

        // ---- accumulate plane t into racc[t] (dt=0) and racc[t-1] (dt=1) ----
        if (hh < 7) {
            const float* p = &bp[cc * LROW + hh * 8];
            float p2[8];
#pragma unroll
            for (int x2 = 0; x2 < 4; ++x2) {
                f2v a = *(const f2v*)(p + 2 * x2);
                f2v bq = *(const f2v*)(p + 8 + 2 * x2);
                f2v s = a + bq;           // y-pool (rows hh, hh+1)
                p2[2 * x2] = s[0];
                p2[2 * x2 + 1] = s[1];
            }
#pragma unroll
            for (int w = 0; w < OW; ++w) {
                float pw = p2[w] + p2[w + 1];   // x-pool
                if (t < OT) racc[t][w] += pw;
                if (t > 0) racc[t - 1][w] += pw;
            }
        }
    }
    __syncthreads();  // plane dbuf dead; scratch reused for flush staging

    // ---- flush in 2 t-pair passes (staging 6272 floats fits the dbuf region) ----
    float* outb = out + ((size_t)r * C_ + c0) * (OT * OH * OW);
#pragma unroll
    for (int tp = 0; tp < 2; ++tp) {
        if (hh < 7) {
            int base = cc * 98 + hh * 7;
#pragma unroll
            for (int tt = 0; tt < 2; ++tt)
#pragma unroll
                for (int w = 0; w < OW; ++w)
                    scratch[base + tt * 49 + w] = racc[2 * tp + tt][w] * 0.125f;
        }
        __syncthreads();
        {
            const f2v* s2 = (const f2v*)scratch;
            f2v* o2 = (f2v*)(outb + tp * 98);
            for (int k = 0; k < 7; ++k) {
                int j = k * 512 + (int)threadIdx.x;
                if (j < 3136) {
                    int c = j / 49;
                    int qf = j - c * 49;
                    // normal store (not NT): L2 merges the half-line boundaries
                    o2[c * 98 + qf] = s2[j];
                }
            }
        }
        if (tp == 0) __syncthreads();   // staging reused by pass 1
    }
}

// ---------------- fallback: direct gather, one thread per output ----------------
__device__ __forceinline__ void axis_sample(float start, float end, float size, int n,
                                            int j, int& lo_i, int& hi_i, float& frac,
                                            float& valid) {
    float length = fmaxf(end - start + 1.0f, 1.0f);
    float step = length / (float)(n - 1);
    float coord = start + step * (float)j;
    valid = (coord >= 0.0f && coord < size) ? 1.0f : 0.0f;
    float lo = fminf(fmaxf(floorf(coord), 0.0f), size - 1.0f);
    frac = coord - lo;
    lo_i = (int)lo;
    hi_i = min(lo_i + 1, (int)size - 1);
}

__global__ void roi_direct(const float* __restrict__ f, const float* __restrict__ rois,
                           float* __restrict__ out, long long total) {
    long long idx = (long long)blockIdx.x * 256 + threadIdx.x;
    if (idx >= total) return;
    int w = (int)(idx % OW);
    long long q = idx / OW;
    int h = (int)(q % OH);
    q /= OH;
    int t = (int)(q % OT);
    q /= OT;
    int c = (int)(q % C_);
    int r = (int)(q / C_);

    float rb = rois[r * 7 + 0];
    float x1 = rois[r * 7 + 1] * SSCALE;
    float y1 = rois[r * 7 + 2] * SSCALE;
    float x2 = rois[r * 7 + 3] * SSCALE;
    float y2 = rois[r * 7 + 4] * SSCALE;
    float t1 = rois[r * 7 + 5] * TSCALE;
    float t2 = rois[r * 7 + 6] * TSCALE;
    int b = (int)rb;
    const float* fc = f + ((size_t)b * C_ + c) * (T_ * H_ * W_);

    float acc = 0.0f;
    for (int dt = 0; dt < 2; ++dt) {
        int tlo, thi; float tf, tv;
        axis_sample(t1, t2, (float)T_, PT, t + dt, tlo, thi, tf, tv);
        for (int dh = 0; dh < 2; ++dh) {
            int ylo, yhi; float yf, yv;
            axis_sample(y1, y2, (float)H_, PH, h + dh, ylo, yhi, yf, yv);
            for (int dw = 0; dw < 2; ++dw) {
                int xlo, xhi; float xf, xv;
                axis_sample(x1, x2, (float)W_, PW, w + dw, xlo, xhi, xf, xv);
                float v000 = fc[(tlo * H_ + ylo) * W_ + xlo];
                float v001 = fc[(tlo * H_ + ylo) * W_ + xhi];
                float v010 = fc[(tlo * H_ + yhi) * W_ + xlo];
                float v011 = fc[(tlo * H_ + yhi) * W_ + xhi];
                float v100 = fc[(thi * H_ + ylo) * W_ + xlo];
                float v101 = fc[(thi * H_ + ylo) * W_ + xhi];
                float v110 = fc[(thi * H_ + yhi) * W_ + xlo];
                float v111 = fc[(thi * H_ + yhi) * W_ + xhi];
                float vx00 = v000 + xf * (v001 - v000);
                float vx01 = v010 + xf * (v011 - v010);
                float vx10 = v100 + xf * (v101 - v100);
                float vx11 = v110 + xf * (v111 - v110);
                float vy0 = vx00 + yf * (vx01 - vx00);
                float vy1 = vx10 + yf * (vx11 - vx10);
                float v = vy0 + tf * (vy1 - vy0);
                acc += v * (tv * yv * xv);
            }
        }
    }
    out[idx] = acc * 0.125f;
}

extern "C" void kernel_launch(void* const* d_in, const int* in_sizes, int n_in,
                              void* d_out, int out_size, void* d_ws, size_t ws_size,
                              hipStream_t stream) {
    const float* feat = (const float*)d_in[0];
    const float* rois = (const float*)d_in[1];
    float* out = (float*)d_out;
    int nroi = in_sizes[1] / 7;
    int B = in_sizes[0] / (C_ * T_ * H_ * W_);
    size_t ftbytes = (size_t)B * T_ * H_ * W_ * C_ * sizeof(_Float16);
    size_t need = ftbytes + 2048 * sizeof(int);

    if (ws_size >= need && nroi >= 1) {
        _Float16* ft = (_Float16*)d_ws;
        int* perm = (int*)((char*)d_ws + ftbytes);
        dim3 g1(T_ * H_ * W_ / 64 + 1, B);   // last x-block: concurrent roi sort
        transpose_kernel<<<g1, 256, 0, stream>>>(feat, ft, rois, nroi, perm);
        roi_kernel<<<dim3(nroi * (C_ / CG)), 512, 0, stream>>>(ft, rois, perm, out);
    } else {
        long long total = (long long)nroi * C_ * OT * OH * OW;
        roi_direct<<<(int)((total + 255) / 256), 256, 0, stream>>>(feat, rois, out, total);
    }
}

// Round 12
// 529.962 us; speedup vs baseline: 1.2866x; 1.2866x over previous
//
#include <hip/hip_runtime.h>

#define C_ 256
#define T_ 16
#define H_ 64
#define W_ 64
#define PT 5
#define PH 8
#define PW 8
#define OT 4
#define OH 7
#define OW 7
#define SSCALE (1.0f/16.0f)
#define TSCALE 1.0f
#define CG 64               /* channels per roi block */
#define LROW 66             /* plane col stride: 8B-aligned f2v pool reads */
#define PLN (CG * LROW)     /* 4224 floats per plane buffer */
#define NOUT (CG * OT * OH * OW)   /* 12544 outputs per block */

typedef float f4v __attribute__((ext_vector_type(4)));
typedef float f2v __attribute__((ext_vector_type(2)));
typedef _Float16 h2v __attribute__((ext_vector_type(2)));
typedef _Float16 h8v __attribute__((ext_vector_type(8)));

__device__ __forceinline__ f4v lo4(h8v h) {
    f4v r = {(float)h[0], (float)h[1], (float)h[2], (float)h[3]};
    return r;
}
__device__ __forceinline__ f4v hi4(h8v h) {
    f4v r = {(float)h[4], (float)h[5], (float)h[6], (float)h[7]};
    return r;
}

// ---------------- transpose+cvt (B,C,T,H,W) f32 -> (B,T,H,W,C) fp16 ----------------
// Read-roofline-bound. The LAST x-block (blockIdx.x == gridDim.x-1, y==0) runs
// the Morton roi sort CONCURRENTLY with the transpose (no serial sort dispatch).
__global__ __launch_bounds__(256) void transpose_kernel(const float* __restrict__ f,
                                                        _Float16* __restrict__ ft,
                                                        const float* __restrict__ rois,
                                                        int nroi, int* __restrict__ perm) {
    __shared__ unsigned tile[64 * 128];   // 32 KB (sort reuses first 8 KB)
    const int THW = T_ * H_ * W_;

    if (blockIdx.x == gridDim.x - 1) {    // sort block (grid.x = THW/64 + 1)
        if (blockIdx.y != 0) return;
        unsigned* key = tile;
        int t = threadIdx.x;
        if (nroi > 2048) {
            for (int i = t; i < nroi; i += 256) perm[i] = i;
            return;
        }
        for (int i = t; i < 2048; i += 256) {
            unsigned k = 0x1FFFFFu;
            if (i < nroi) {
                const float* rp = rois + i * 7;
                int bb = (int)rp[0];
                float xc = (rp[1] + rp[3]) * 0.5f * SSCALE;
                float yc = (rp[2] + rp[4]) * 0.5f * SSCALE;
                float tc = (rp[5] + rp[6]) * 0.5f * TSCALE;
                int xq = min(63, max(0, (int)xc));
                int yq = min(63, max(0, (int)yc));
                int tq = min(15, max(0, (int)tc));
                unsigned m = 0;
#pragma unroll
                for (int bit = 0; bit < 6; ++bit)
                    m |= (((yq >> bit) & 1u) << (2 * bit + 1)) |
                         (((xq >> bit) & 1u) << (2 * bit));
                k = ((((unsigned)bb << 12) | m) << 4) | (unsigned)tq;
            }
            key[i] = (k << 11) | (unsigned)i;
        }
        __syncthreads();
        for (int kk = 2; kk <= 2048; kk <<= 1) {
            for (int j = kk >> 1; j > 0; j >>= 1) {
                for (int i = t; i < 2048; i += 256) {
                    int ixj = i ^ j;
                    if (ixj > i) {
                        unsigned a = key[i], c = key[ixj];
                        bool up = (i & kk) == 0;
                        if ((a > c) == up) { key[i] = c; key[ixj] = a; }
                    }
                }
                __syncthreads();
            }
        }
        for (int i = t; i < 2048; i += 256)
            if (i < nroi) perm[i] = (int)(key[i] & 0x7FFu);
        return;
    }

    // ---- transpose path: channel-pair packed u32 tile, XOR swizzle ----
    int thw0 = blockIdx.x * 64;
    int b = blockIdx.y;
    int q = threadIdx.x & 15;      // thw quad
    int cp0 = threadIdx.x >> 4;    // 0..15

#pragma unroll
    for (int k = 0; k < 8; ++k) {
        int cp = k * 16 + cp0;     // channel pair 0..127
        int c = cp * 2;
        const f4v* s0 = reinterpret_cast<const f4v*>(
            &f[((size_t)b * C_ + c) * THW + thw0 + q * 4]);
        const f4v* s1 = reinterpret_cast<const f4v*>(
            &f[((size_t)b * C_ + c + 1) * THW + thw0 + q * 4]);
        f4v va = __builtin_nontemporal_load(s0);
        f4v vb = __builtin_nontemporal_load(s1);
#pragma unroll
        for (int j = 0; j < 4; ++j) {
            int row = q * 4 + j;
            h2v hp = {(_Float16)va[j], (_Float16)vb[j]};
            tile[row * 128 + (cp ^ (row & 30))] = __builtin_bit_cast(unsigned, hp);
        }
    }
    __syncthreads();

    int wv = threadIdx.x >> 6;     // wave 0..3
    int ln = threadIdx.x & 63;
    size_t orow = ((size_t)b * THW + thw0) * C_;
#pragma unroll
    for (int i = 0; i < 16; ++i) {
        int row = wv * 16 + i;
        int s = row & 30;          // even -> pair-preserving XOR -> b64 read
        uint2 w = *reinterpret_cast<const uint2*>(&tile[row * 128 + ((ln * 2) ^ s)]);
        *reinterpret_cast<uint2*>(&ft[orow + (size_t)row * C_ + ln * 4]) = w;
    }
}

// ---------------- main: one 512-thread block per (sorted roi, 64-channel group) ----
// Rolling 2-entry row-plane cache (loads 40 -> ~16-24/thread). LDS = 33.8KB
// plane dbuf only (flush split into 2 t-pair passes staged in the dead dbuf
// region). NO min-waves force: round-11's (512,8) pinned VGPR=32 -> spills
// (WRITE 235->601MB, dur 2x). Let the allocator pick (~56-64 VGPR, no spill);
// 4 blocks/CU materializes iff VGPR<=64.
__global__ __launch_bounds__(512) void roi_kernel(const _Float16* __restrict__ ft,
                                                  const float* __restrict__ rois,
                                                  const int* __restrict__ perm,
                                                  float* __restrict__ out) {
    __shared__ float scratch[2 * PLN];  // 33792 B: plane dbuf; later flush staging
    __shared__ float sroi[7];
    __shared__ int2 s_trow[PT]; __shared__ float2 s_twt[PT];
    __shared__ int2 s_yrow[PH]; __shared__ float2 s_ywt[PH];
    __shared__ int2 s_xoff[PW]; __shared__ float2 s_xwt[PW];

    int bid = blockIdx.x;
    int r = perm[bid >> 2];
    int cg = bid & 3;
    int c0 = cg * CG;

    if (threadIdx.x < 7) sroi[threadIdx.x] = rois[r * 7 + threadIdx.x];
    __syncthreads();

    // axis tables: byte offsets (lo/hi) + validity-folded weights
    if (threadIdx.x < 21) {
        int i = threadIdx.x;
        float start, end, size;
        int j, n, scale;
        if (i < 5) {
            j = i; n = PT;
            start = sroi[5] * TSCALE; end = sroi[6] * TSCALE;
            size = (float)T_; scale = H_ * W_ * C_ * 2;
        } else if (i < 13) {
            j = i - 5; n = PH;
            start = sroi[2] * SSCALE; end = sroi[4] * SSCALE;
            size = (float)H_; scale = W_ * C_ * 2;
        } else {
            j = i - 13; n = PW;
            start = sroi[1] * SSCALE; end = sroi[3] * SSCALE;
            size = (float)W_; scale = C_ * 2;
        }
        float length = fmaxf(end - start + 1.0f, 1.0f);
        float step = length / (float)(n - 1);
        float coord = start + step * (float)j;
        float valid = (coord >= 0.0f && coord < size) ? 1.0f : 0.0f;
        float lo = fminf(fmaxf(floorf(coord), 0.0f), size - 1.0f);
        int lo_i = (int)lo;
        int hi_i = min(lo_i + 1, (int)size - 1);
        float fr = coord - lo;
        int2 offs; offs.x = lo_i * scale; offs.y = hi_i * scale;
        float2 wts; wts.x = (1.0f - fr) * valid; wts.y = fr * valid;
        if (i < 5)       { s_trow[j] = offs; s_twt[j] = wts; }
        else if (i < 13) { s_yrow[j] = offs; s_ywt[j] = wts; }
        else             { s_xoff[j] = offs; s_xwt[j] = wts; }
    }
    __syncthreads();

    int b = (int)sroi[0];
    int c8 = threadIdx.x & 7;     // half8 lane: 8 lanes x 8 ch = 64 channels
    int slot = threadIdx.x >> 3;  // 0..63 sample slot
    const char* fb = (const char*)ft
        + ((size_t)b * (T_ * H_ * W_ * C_) + (size_t)(c0 + c8 * 8)) * 2;

    float* bufs[2] = {scratch, scratch + PLN};
    int cc = threadIdx.x & 63;
    int hh = threadIdx.x >> 6;    // 0..7; hh==7 idle for pooling

    float racc[OT][OW];
#pragma unroll
    for (int t = 0; t < OT; ++t)
#pragma unroll
        for (int w = 0; w < OW; ++w) racc[t][w] = 0.0f;

    int y = slot >> 3, x = slot & 7;
    int2 yr = s_yrow[y]; float2 yw = s_ywt[y];
    int2 xo = s_xoff[x]; float2 xw = s_xwt[x];
    int o00 = yr.x + xo.x, o01 = yr.x + xo.y;
    int o10 = yr.y + xo.x, o11 = yr.y + xo.y;

    // rolling row-plane cache: slot A (row ia), slot B (row ib)
    int ia = -1, ib = -1;
    f4v aL, aH, bL, bH;
    aL = aH = bL = bH = (f4v){0.f, 0.f, 0.f, 0.f};

#pragma unroll
    for (int t = 0; t < PT; ++t) {
        int2 trv = s_trow[t];
        int trx = __builtin_amdgcn_readfirstlane(trv.x);
        int trY = __builtin_amdgcn_readfirstlane(trv.y);
        float2 tw = s_twt[t];

        if (ia != trx) {
            if (ib == trx) { aL = bL; aH = bH; ia = trx; }
            else {
                h8v q00 = *(const h8v*)(fb + trx + o00);
                h8v q01 = *(const h8v*)(fb + trx + o01);
                h8v q10 = *(const h8v*)(fb + trx + o10);
                h8v q11 = *(const h8v*)(fb + trx + o11);
                aL = yw.x * (xw.x * lo4(q00) + xw.y * lo4(q01))
                   + yw.y * (xw.x * lo4(q10) + xw.y * lo4(q11));
                aH = yw.x * (xw.x * hi4(q00) + xw.y * hi4(q01))
                   + yw.y * (xw.x * hi4(q10) + xw.y * hi4(q11));
                ia = trx;
            }
        }
        if (ib != trY) {
            if (ia == trY) { bL = aL; bH = aH; ib = trY; }
            else {
                h8v p00 = *(const h8v*)(fb + trY + o00);
                h8v p01 = *(const h8v*)(fb + trY + o01);
                h8v p10 = *(const h8v*)(fb + trY + o10);
                h8v p11 = *(const h8v*)(fb + trY + o11);
                bL = yw.x * (xw.x * lo4(p00) + xw.y * lo4(p01))
                   + yw.y * (xw.x * lo4(p10) + xw.y * lo4(p11));
                bH = yw.x * (xw.x * hi4(p00) + xw.y * hi4(p01))
                   + yw.y * (xw.x * hi4(p10) + xw.y * hi4(p11));
                ib = trY;
            }
        }

        f4v vL = tw.x * aL + tw.y * bL;
        f4v vH = tw.x * aH + tw.y * bH;

        float* bp = bufs[t & 1];
        {
            float* col = &bp[(c8 * 8) * LROW + slot];
            col[0 * LROW] = vL[0];
            col[1 * LROW] = vL[1];
            col[2 * LROW] = vL[2];
            col[3 * LROW] = vL[3];
            col[4 * LROW] = vH[0];
            col[5 * LROW] = vH[1];
            col[6 * LROW] = vH[2];
            col[7 * LROW] = vH[3];
        }
        __syncthreads();   // single barrier/plane: next write hits other buffer

        // ---- accumulate plane t into racc[t] (dt=0) and racc[t-1] (dt=1) ----
        if (hh < 7) {
            const float* p = &bp[cc * LROW + hh * 8];
            float p2[8];
#pragma unroll
            for (int x2 = 0; x2 < 4; ++x2) {
                f2v a = *(const f2v*)(p + 2 * x2);
                f2v bq = *(const f2v*)(p + 8 + 2 * x2);
                f2v s = a + bq;           // y-pool (rows hh, hh+1)
                p2[2 * x2] = s[0];
                p2[2 * x2 + 1] = s[1];
            }
#pragma unroll
            for (int w = 0; w < OW; ++w) {
                float pw = p2[w] + p2[w + 1];   // x-pool
                if (t < OT) racc[t][w] += pw;
                if (t > 0) racc[t - 1][w] += pw;
            }
        }
    }
    __syncthreads();  // plane dbuf dead; scratch reused for flush staging

    // ---- flush in 2 t-pair passes (staging 6272 floats fits the dbuf region) ----
    float* outb = out + ((size_t)r * C_ + c0) * (OT * OH * OW);
#pragma unroll
    for (int tp = 0; tp < 2; ++tp) {
        if (hh < 7) {
            int base = cc * 98 + hh * 7;
#pragma unroll
            for (int tt = 0; tt < 2; ++tt)
#pragma unroll
                for (int w = 0; w < OW; ++w)
                    scratch[base + tt * 49 + w] = racc[2 * tp + tt][w] * 0.125f;
        }
        __syncthreads();
        {
            const f2v* s2 = (const f2v*)scratch;
            f2v* o2 = (f2v*)(outb + tp * 98);
            for (int k = 0; k < 7; ++k) {
                int j = k * 512 + (int)threadIdx.x;
                if (j < 3136) {
                    int c = j / 49;
                    int qf = j - c * 49;
                    // normal store (not NT): L2 merges the half-line boundaries
                    o2[c * 98 + qf] = s2[j];
                }
            }
        }
        if (tp == 0) __syncthreads();   // staging reused by pass 1
    }
}

// ---------------- fallback: direct gather, one thread per output ----------------
__device__ __forceinline__ void axis_sample(float start, float end, float size, int n,
                                            int j, int& lo_i, int& hi_i, float& frac,
                                            float& valid) {
    float length = fmaxf(end - start + 1.0f, 1.0f);
    float step = length / (float)(n - 1);
    float coord = start + step * (float)j;
    valid = (coord >= 0.0f && coord < size) ? 1.0f : 0.0f;
    float lo = fminf(fmaxf(floorf(coord), 0.0f), size - 1.0f);
    frac = coord - lo;
    lo_i = (int)lo;
    hi_i = min(lo_i + 1, (int)size - 1);
}

__global__ void roi_direct(const float* __restrict__ f, const float* __restrict__ rois,
                           float* __restrict__ out, long long total) {
    long long idx = (long long)blockIdx.x * 256 + threadIdx.x;
    if (idx >= total) return;
    int w = (int)(idx % OW);
    long long q = idx / OW;
    int h = (int)(q % OH);
    q /= OH;
    int t = (int)(q % OT);
    q /= OT;
    int c = (int)(q % C_);
    int r = (int)(q / C_);

    float rb = rois[r * 7 + 0];
    float x1 = rois[r * 7 + 1] * SSCALE;
    float y1 = rois[r * 7 + 2] * SSCALE;
    float x2 = rois[r * 7 + 3] * SSCALE;
    float y2 = rois[r * 7 + 4] * SSCALE;
    float t1 = rois[r * 7 + 5] * TSCALE;
    float t2 = rois[r * 7 + 6] * TSCALE;
    int b = (int)rb;
    const float* fc = f + ((size_t)b * C_ + c) * (T_ * H_ * W_);

    float acc = 0.0f;
    for (int dt = 0; dt < 2; ++dt) {
        int tlo, thi; float tf, tv;
        axis_sample(t1, t2, (float)T_, PT, t + dt, tlo, thi, tf, tv);
        for (int dh = 0; dh < 2; ++dh) {
            int ylo, yhi; float yf, yv;
            axis_sample(y1, y2, (float)H_, PH, h + dh, ylo, yhi, yf, yv);
            for (int dw = 0; dw < 2; ++dw) {
                int xlo, xhi; float xf, xv;
                axis_sample(x1, x2, (float)W_, PW, w + dw, xlo, xhi, xf, xv);
                float v000 = fc[(tlo * H_ + ylo) * W_ + xlo];
                float v001 = fc[(tlo * H_ + ylo) * W_ + xhi];
                float v010 = fc[(tlo * H_ + yhi) * W_ + xlo];
                float v011 = fc[(tlo * H_ + yhi) * W_ + xhi];
                float v100 = fc[(thi * H_ + ylo) * W_ + xlo];
                float v101 = fc[(thi * H_ + ylo) * W_ + xhi];
                float v110 = fc[(thi * H_ + yhi) * W_ + xlo];
                float v111 = fc[(thi * H_ + yhi) * W_ + xhi];
                float vx00 = v000 + xf * (v001 - v000);
                float vx01 = v010 + xf * (v011 - v010);
                float vx10 = v100 + xf * (v101 - v100);
                float vx11 = v110 + xf * (v111 - v110);
                float vy0 = vx00 + yf * (vx01 - vx00);
                float vy1 = vx10 + yf * (vx11 - vx10);
                float v = vy0 + tf * (vy1 - vy0);
                acc += v * (tv * yv * xv);
            }
        }
    }
    out[idx] = acc * 0.125f;
}

extern "C" void kernel_launch(void* const* d_in, const int* in_sizes, int n_in,
                              void* d_out, int out_size, void* d_ws, size_t ws_size,
                              hipStream_t stream) {
    const float* feat = (const float*)d_in[0];
    const float* rois = (const float*)d_in[1];
    float* out = (float*)d_out;
    int nroi = in_sizes[1] / 7;
    int B = in_sizes[0] / (C_ * T_ * H_ * W_);
    size_t ftbytes = (size_t)B * T_ * H_ * W_ * C_ * sizeof(_Float16);
    size_t need = ftbytes + 2048 * sizeof(int);

    if (ws_size >= need && nroi >= 1) {
        _Float16* ft = (_Float16*)d_ws;
        int* perm = (int*)((char*)d_ws + ftbytes);
        dim3 g1(T_ * H_ * W_ / 64 + 1, B);   // last x-block: concurrent roi sort
        transpose_kernel<<<g1, 256, 0, stream>>>(feat, ft, rois, nroi, perm);
        roi_kernel<<<dim3(nroi * (C_ / CG)), 512, 0, stream>>>(ft, rois, perm, out);
    } else {
        long long total = (long long)nroi * C_ * OT * OH * OW;
        roi_direct<<<(int)((total + 255) / 256), 256, 0, stream>>>(feat, rois, out, total);
    }
}

// Round 13
// 513.991 us; speedup vs baseline: 1.3265x; 1.0311x over previous
//
#include <hip/hip_runtime.h>

#define C_ 256
#define T_ 16
#define H_ 64
#define W_ 64
#define PT 5
#define PH 8
#define PW 8
#define OT 4
#define OH 7
#define OW 7
#define SSCALE (1.0f/16.0f)
#define TSCALE 1.0f
#define CG 64               /* channels per roi block */
#define LROW 66             /* plane col stride: 8B-aligned f2v pool reads */
#define PLN (CG * LROW)     /* 4224 floats per plane buffer */
#define NOUT (CG * OT * OH * OW)   /* 12544 outputs per block */

typedef float f4v __attribute__((ext_vector_type(4)));
typedef float f2v __attribute__((ext_vector_type(2)));
typedef _Float16 h2v __attribute__((ext_vector_type(2)));
typedef _Float16 h8v __attribute__((ext_vector_type(8)));

__device__ __forceinline__ f4v lo4(h8v h) {
    f4v r = {(float)h[0], (float)h[1], (float)h[2], (float)h[3]};
    return r;
}
__device__ __forceinline__ f4v hi4(h8v h) {
    f4v r = {(float)h[4], (float)h[5], (float)h[6], (float)h[7]};
    return r;
}

// ---------------- transpose+cvt (B,C,T,H,W) f32 -> (B,T,H,W,C) fp16 ----------------
// At BW roofline (~640 MB): channel-pair packed u32 LDS tile, XOR swizzle,
// coalesced 256B NT reads, full 512B ft line stores.
__global__ __launch_bounds__(256) void transpose_kernel(const float* __restrict__ f,
                                                        _Float16* __restrict__ ft) {
    __shared__ unsigned tile[64 * 128];   // 32 KB
    const int THW = T_ * H_ * W_;
    int thw0 = blockIdx.x * 64;
    int b = blockIdx.y;
    int q = threadIdx.x & 15;      // thw quad
    int cp0 = threadIdx.x >> 4;    // 0..15

#pragma unroll
    for (int k = 0; k < 8; ++k) {
        int cp = k * 16 + cp0;     // channel pair 0..127
        int c = cp * 2;
        const f4v* s0 = reinterpret_cast<const f4v*>(
            &f[((size_t)b * C_ + c) * THW + thw0 + q * 4]);
        const f4v* s1 = reinterpret_cast<const f4v*>(
            &f[((size_t)b * C_ + c + 1) * THW + thw0 + q * 4]);
        f4v va = __builtin_nontemporal_load(s0);
        f4v vb = __builtin_nontemporal_load(s1);
#pragma unroll
        for (int j = 0; j < 4; ++j) {
            int row = q * 4 + j;
            h2v hp = {(_Float16)va[j], (_Float16)vb[j]};
            tile[row * 128 + (cp ^ (row & 30))] = __builtin_bit_cast(unsigned, hp);
        }
    }
    __syncthreads();

    int wv = threadIdx.x >> 6;     // wave 0..3
    int ln = threadIdx.x & 63;
    size_t orow = ((size_t)b * THW + thw0) * C_;
#pragma unroll
    for (int i = 0; i < 16; ++i) {
        int row = wv * 16 + i;
        int s = row & 30;          // even -> pair-preserving XOR -> b64 read
        uint2 w = *reinterpret_cast<const uint2*>(&tile[row * 128 + ((ln * 2) ^ s)]);
        *reinterpret_cast<uint2*>(&ft[orow + (size_t)row * C_ + ln * 4]) = w;
    }
}

// ---------------- spatial roi sort (Morton order) -> perm ----------------
__global__ __launch_bounds__(1024) void sort_rois(const float* __restrict__ rois,
                                                  int nroi, int* __restrict__ perm) {
    __shared__ unsigned key[2048];
    int t = threadIdx.x;
    if (nroi > 2048) {             // fallback: identity order
        for (int i = t; i < nroi; i += 1024) perm[i] = i;
        return;
    }
    for (int i = t; i < 2048; i += 1024) {
        unsigned k = 0x1FFFFFu;    // pad key sorts to end
        if (i < nroi) {
            const float* rp = rois + i * 7;
            int bb = (int)rp[0];
            float xc = (rp[1] + rp[3]) * 0.5f * SSCALE;
            float yc = (rp[2] + rp[4]) * 0.5f * SSCALE;
            float tc = (rp[5] + rp[6]) * 0.5f * TSCALE;
            int xq = min(63, max(0, (int)xc));
            int yq = min(63, max(0, (int)yc));
            int tq = min(15, max(0, (int)tc));
            unsigned m = 0;
#pragma unroll
            for (int bit = 0; bit < 6; ++bit)
                m |= (((yq >> bit) & 1u) << (2 * bit + 1)) |
                     (((xq >> bit) & 1u) << (2 * bit));
            k = ((((unsigned)bb << 12) | m) << 4) | (unsigned)tq;   // 18 bits
        }
        key[i] = (k << 11) | (unsigned)i;
    }
    __syncthreads();
    for (int kk = 2; kk <= 2048; kk <<= 1) {
        for (int j = kk >> 1; j > 0; j >>= 1) {
            for (int i = t; i < 2048; i += 1024) {
                int ixj = i ^ j;
                if (ixj > i) {
                    unsigned a = key[i], c = key[ixj];
                    bool up = (i & kk) == 0;
                    if ((a > c) == up) { key[i] = c; key[ixj] = a; }
                }
            }
            __syncthreads();
        }
    }
    for (int i = t; i < 2048; i += 1024)
        if (i < nroi) perm[i] = (int)(key[i] & 0x7FFu);
}

// ---------------- main: one 512-thread block per (sorted roi, 64-channel group) ----
// roi is LOAD-ISSUE-bound (40 vmem/thread = 160us floor). Fix: rolling 2-entry
// row-plane cache. Consecutive t-planes share t-rows (monotone t samples); the
// xy-interpolated row-plane is cached in registers, so a reused row costs zero
// loads. Loads/thread drop 40 -> ~16-24. Arithmetic order identical to before.
__global__ __launch_bounds__(512) void roi_kernel(const _Float16* __restrict__ ft,
                                                  const float* __restrict__ rois,
                                                  const int* __restrict__ perm,
                                                  float* __restrict__ out) {
    __shared__ float scratch[NOUT];  // 50176 B; first 2*4224 floats = plane dbuf
    __shared__ float sroi[7];
    __shared__ int2 s_trow[PT]; __shared__ float2 s_twt[PT];
    __shared__ int2 s_yrow[PH]; __shared__ float2 s_ywt[PH];
    __shared__ int2 s_xoff[PW]; __shared__ float2 s_xwt[PW];

    int bid = blockIdx.x;
    int r = perm[bid >> 2];
    int cg = bid & 3;
    int c0 = cg * CG;

    if (threadIdx.x < 7) sroi[threadIdx.x] = rois[r * 7 + threadIdx.x];
    __syncthreads();

    // axis tables: byte offsets (lo/hi) + validity-folded weights
    if (threadIdx.x < 21) {
        int i = threadIdx.x;
        float start, end, size;
        int j, n, scale;
        if (i < 5) {
            j = i; n = PT;
            start = sroi[5] * TSCALE; end = sroi[6] * TSCALE;
            size = (float)T_; scale = H_ * W_ * C_ * 2;
        } else if (i < 13) {
            j = i - 5; n = PH;
            start = sroi[2] * SSCALE; end = sroi[4] * SSCALE;
            size = (float)H_; scale = W_ * C_ * 2;
        } else {
            j = i - 13; n = PW;
            start = sroi[1] * SSCALE; end = sroi[3] * SSCALE;
            size = (float)W_; scale = C_ * 2;
        }
        float length = fmaxf(end - start + 1.0f, 1.0f);
        float step = length / (float)(n - 1);
        float coord = start + step * (float)j;
        float valid = (coord >= 0.0f && coord < size) ? 1.0f : 0.0f;
        float lo = fminf(fmaxf(floorf(coord), 0.0f), size - 1.0f);
        int lo_i = (int)lo;
        int hi_i = min(lo_i + 1, (int)size - 1);
        float fr = coord - lo;
        int2 offs; offs.x = lo_i * scale; offs.y = hi_i * scale;
        float2 wts; wts.x = (1.0f - fr) * valid; wts.y = fr * valid;
        if (i < 5)       { s_trow[j] = offs; s_twt[j] = wts; }
        else if (i < 13) { s_yrow[j] = offs; s_ywt[j] = wts; }
        else             { s_xoff[j] = offs; s_xwt[j] = wts; }
    }
    __syncthreads();

    int b = (int)sroi[0];
    int c8 = threadIdx.x & 7;     // half8 lane: 8 lanes x 8 ch = 64 channels
    int slot = threadIdx.x >> 3;  // 0..63 sample slot
    const char* fb = (const char*)ft
        + ((size_t)b * (T_ * H_ * W_ * C_) + (size_t)(c0 + c8 * 8)) * 2;

    float* bufs[2] = {scratch, scratch + PLN};
    int cc = threadIdx.x & 63;
    int hh = threadIdx.x >> 6;    // 0..7; hh==7 idle for pooling

    float racc[OT][OW];
#pragma unroll
    for (int t = 0; t < OT; ++t)
#pragma unroll
        for (int w = 0; w < OW; ++w) racc[t][w] = 0.0f;

    int y = slot >> 3, x = slot & 7;
    int2 yr = s_yrow[y]; float2 yw = s_ywt[y];
    int2 xo = s_xoff[x]; float2 xw = s_xwt[x];
    int o00 = yr.x + xo.x, o01 = yr.x + xo.y;
    int o10 = yr.y + xo.x, o11 = yr.y + xo.y;

    // rolling row-plane cache: slot A (row ia), slot B (row ib)
    int ia = -1, ib = -1;
    f4v aL, aH, bL, bH;
    aL = aH = bL = bH = (f4v){0.f, 0.f, 0.f, 0.f};

#pragma unroll
    for (int t = 0; t < PT; ++t) {
        int2 trv = s_trow[t];
        // block-uniform values -> scalar branches
        int trx = __builtin_amdgcn_readfirstlane(trv.x);
        int trY = __builtin_amdgcn_readfirstlane(trv.y);
        float2 tw = s_twt[t];

        if (ia != trx) {
            if (ib == trx) { aL = bL; aH = bH; ia = trx; }
            else {
                h8v q00 = *(const h8v*)(fb + trx + o00);
                h8v q01 = *(const h8v*)(fb + trx + o01);
                h8v q10 = *(const h8v*)(fb + trx + o10);
                h8v q11 = *(const h8v*)(fb + trx + o11);
                aL = yw.x * (xw.x * lo4(q00) + xw.y * lo4(q01))
                   + yw.y * (xw.x * lo4(q10) + xw.y * lo4(q11));
                aH = yw.x * (xw.x * hi4(q00) + xw.y * hi4(q01))
                   + yw.y * (xw.x * hi4(q10) + xw.y * hi4(q11));
                ia = trx;
            }
        }
        if (ib != trY) {
            if (ia == trY) { bL = aL; bH = aH; ib = trY; }
            else {
                h8v p00 = *(const h8v*)(fb + trY + o00);
                h8v p01 = *(const h8v*)(fb + trY + o01);
                h8v p10 = *(const h8v*)(fb + trY + o10);
                h8v p11 = *(const h8v*)(fb + trY + o11);
                bL = yw.x * (xw.x * lo4(p00) + xw.y * lo4(p01))
                   + yw.y * (xw.x * lo4(p10) + xw.y * lo4(p11));
                bH = yw.x * (xw.x * hi4(p00) + xw.y * hi4(p01))
                   + yw.y * (xw.x * hi4(p10) + xw.y * hi4(p11));
                ib = trY;
            }
        }

        f4v vL = tw.x * aL + tw.y * bL;
        f4v vH = tw.x * aH + tw.y * bH;

        float* bp = bufs[t & 1];
        {
            float* col = &bp[(c8 * 8) * LROW + slot];
            col[0 * LROW] = vL[0];
            col[1 * LROW] = vL[1];
            col[2 * LROW] = vL[2];
            col[3 * LROW] = vL[3];
            col[4 * LROW] = vH[0];
            col[5 * LROW] = vH[1];
            col[6 * LROW] = vH[2];
            col[7 * LROW] = vH[3];
        }
        __syncthreads();   // single barrier/plane: next write hits other buffer

        // ---- accumulate plane t into racc[t] (dt=0) and racc[t-1] (dt=1) ----
        if (hh < 7) {
            const float* p = &bp[cc * LROW + hh * 8];
            float p2[8];
#pragma unroll
            for (int x2 = 0; x2 < 4; ++x2) {
                f2v a = *(const f2v*)(p + 2 * x2);
                f2v bq = *(const f2v*)(p + 8 + 2 * x2);
                f2v s = a + bq;           // y-pool (rows hh, hh+1)
                p2[2 * x2] = s[0];
                p2[2 * x2 + 1] = s[1];
            }
#pragma unroll
            for (int w = 0; w < OW; ++w) {
                float pw = p2[w] + p2[w + 1];   // x-pool
                if (t < OT) racc[t][w] += pw;
                if (t > 0) racc[t - 1][w] += pw;
            }
        }
    }
    __syncthreads();  // plane dbuf dead; scratch reused for flush

    // ---- stage pooled outputs in (c,t,h,w) order, flush coalesced ----
    if (hh < 7) {
        int base = cc * (OT * OH * OW) + hh * OW;
#pragma unroll
        for (int t = 0; t < OT; ++t)
#pragma unroll
            for (int w = 0; w < OW; ++w)
                scratch[base + t * (OH * OW) + w] = racc[t][w] * 0.125f;
    }
    __syncthreads();

    float* outb = out + ((size_t)r * C_ + c0) * (OT * OH * OW);
    const f4v* s4 = (const f4v*)scratch;
    f4v* o4 = (f4v*)outb;
#pragma unroll
    for (int k = 0; k < 7; ++k) {
        int idx = k * 512 + threadIdx.x;
        if (idx < NOUT / 4) __builtin_nontemporal_store(s4[idx], &o4[idx]);
    }
}

// ---------------- fallback: direct gather, one thread per output ----------------
__device__ __forceinline__ void axis_sample(float start, float end, float size, int n,
                                            int j, int& lo_i, int& hi_i, float& frac,
                                            float& valid) {
    float length = fmaxf(end - start + 1.0f, 1.0f);
    float step = length / (float)(n - 1);
    float coord = start + step * (float)j;
    valid = (coord >= 0.0f && coord < size) ? 1.0f : 0.0f;
    float lo = fminf(fmaxf(floorf(coord), 0.0f), size - 1.0f);
    frac = coord - lo;
    lo_i = (int)lo;
    hi_i = min(lo_i + 1, (int)size - 1);
}

__global__ void roi_direct(const float* __restrict__ f, const float* __restrict__ rois,
                           float* __restrict__ out, long long total) {
    long long idx = (long long)blockIdx.x * 256 + threadIdx.x;
    if (idx >= total) return;
    int w = (int)(idx % OW);
    long long q = idx / OW;
    int h = (int)(q % OH);
    q /= OH;
    int t = (int)(q % OT);
    q /= OT;
    int c = (int)(q % C_);
    int r = (int)(q / C_);

    float rb = rois[r * 7 + 0];
    float x1 = rois[r * 7 + 1] * SSCALE;
    float y1 = rois[r * 7 + 2] * SSCALE;
    float x2 = rois[r * 7 + 3] * SSCALE;
    float y2 = rois[r * 7 + 4] * SSCALE;
    float t1 = rois[r * 7 + 5] * TSCALE;
    float t2 = rois[r * 7 + 6] * TSCALE;
    int b = (int)rb;
    const float* fc = f + ((size_t)b * C_ + c) * (T_ * H_ * W_);

    float acc = 0.0f;
    for (int dt = 0; dt < 2; ++dt) {
        int tlo, thi; float tf, tv;
        axis_sample(t1, t2, (float)T_, PT, t + dt, tlo, thi, tf, tv);
        for (int dh = 0; dh < 2; ++dh) {
            int ylo, yhi; float yf, yv;
            axis_sample(y1, y2, (float)H_, PH, h + dh, ylo, yhi, yf, yv);
            for (int dw = 0; dw < 2; ++dw) {
                int xlo, xhi; float xf, xv;
                axis_sample(x1, x2, (float)W_, PW, w + dw, xlo, xhi, xf, xv);
                float v000 = fc[(tlo * H_ + ylo) * W_ + xlo];
                float v001 = fc[(tlo * H_ + ylo) * W_ + xhi];
                float v010 = fc[(tlo * H_ + yhi) * W_ + xlo];
                float v011 = fc[(tlo * H_ + yhi) * W_ + xhi];
                float v100 = fc[(thi * H_ + ylo) * W_ + xlo];
                float v101 = fc[(thi * H_ + ylo) * W_ + xhi];
                float v110 = fc[(thi * H_ + yhi) * W_ + xlo];
                float v111 = fc[(thi * H_ + yhi) * W_ + xhi];
                float vx00 = v000 + xf * (v001 - v000);
                float vx01 = v010 + xf * (v011 - v010);
                float vx10 = v100 + xf * (v101 - v100);
                float vx11 = v110 + xf * (v111 - v110);
                float vy0 = vx00 + yf * (vx01 - vx00);
                float vy1 = vx10 + yf * (vx11 - vx10);
                float v = vy0 + tf * (vy1 - vy0);
                acc += v * (tv * yv * xv);
            }
        }
    }
    out[idx] = acc * 0.125f;
}

extern "C" void kernel_launch(void* const* d_in, const int* in_sizes, int n_in,
                              void* d_out, int out_size, void* d_ws, size_t ws_size,
                              hipStream_t stream) {
    const float* feat = (const float*)d_in[0];
    const float* rois = (const float*)d_in[1];
    float* out = (float*)d_out;
    int nroi = in_sizes[1] / 7;
    int B = in_sizes[0] / (C_ * T_ * H_ * W_);
    size_t ftbytes = (size_t)B * T_ * H_ * W_ * C_ * sizeof(_Float16);
    size_t need = ftbytes + 2048 * sizeof(int);

    if (ws_size >= need && nroi >= 1) {
        _Float16* ft = (_Float16*)d_ws;
        int* perm = (int*)((char*)d_ws + ftbytes);
        sort_rois<<<1, 1024, 0, stream>>>(rois, nroi, perm);
        dim3 g1(T_ * H_ * W_ / 64, B);
        transpose_kernel<<<g1, 256, 0, stream>>>(feat, ft);
        roi_kernel<<<dim3(nroi * (C_ / CG)), 512, 0, stream>>>(ft, rois, perm, out);
    } else {
        long long total = (long long)nroi * C_ * OT * OH * OW;
        roi_direct<<<(int)((total + 255) / 256), 256, 0, stream>>>(feat, rois, out, total);
    }
}